// Round 9
// baseline (317.294 us; speedup 1.0000x reference)
//
#include <hip/hip_runtime.h>
#include <hip/hip_bf16.h>

// GCN 2-layer encoder. CSR-gather aggregation + split-bf16 MFMA GEMMs.
// GEMM: occupancy-maximized single-buffer pipeline — 20KB LDS, <=64 VGPR target,
// 8 blocks/CU (32 waves/CU). TLP hides all latency; B preconverted bf16 hi/lo in L2.

typedef __attribute__((ext_vector_type(4))) float f32x4;
typedef __attribute__((ext_vector_type(8))) short short8;
typedef __attribute__((ext_vector_type(8))) unsigned short u16x8;

static __device__ __forceinline__ unsigned short f2bf(float f) {
    unsigned int u = __float_as_uint(f);
    u += 0x7FFF + ((u >> 16) & 1);          // round-to-nearest-even
    return (unsigned short)(u >> 16);
}
static __device__ __forceinline__ float bf2f(unsigned short h) {
    return __uint_as_float(((unsigned int)h) << 16);
}

__global__ void fill_int(int* __restrict__ p, int v, int n) {
    int i = blockIdx.x * blockDim.x + threadIdx.x;
    if (i < n) p[i] = v;
}

__global__ void deg_accum_i(const int* __restrict__ dst, int* __restrict__ deg, int E) {
    int i = blockIdx.x * blockDim.x + threadIdx.x;
    if (i < E) atomicAdd(&deg[dst[i]], 1);
}

__global__ void make_dis(int* __restrict__ deg, int N) {
    int i = blockIdx.x * blockDim.x + threadIdx.x;
    if (i < N) {
        int d = deg[i];
        ((float*)deg)[i] = rsqrtf((float)(d + 1));
    }
}

// ---- hierarchical exclusive scan: deg[N] -> rp[N+1], cursor[N] ----
__global__ void scan_part(const int* __restrict__ deg, int* __restrict__ bsum, int N) {
    int tid = threadIdx.x, lane = tid & 63, wid = tid >> 6;
    int i = blockIdx.x * 256 + tid;
    int v = (i < N) ? deg[i] : 0;
#pragma unroll
    for (int off = 1; off < 64; off <<= 1) v += __shfl_xor(v, off, 64);
    __shared__ int ws[4];
    if (lane == 0) ws[wid] = v;
    __syncthreads();
    if (tid == 0) bsum[blockIdx.x] = ws[0] + ws[1] + ws[2] + ws[3];
}

__global__ __launch_bounds__(1024) void scan_top(const int* __restrict__ bsum, int nb,
                                                 int* __restrict__ boff, int* __restrict__ rp, int N) {
    __shared__ int wsum[16];
    int tid = threadIdx.x, lane = tid & 63, wid = tid >> 6;
    int v = (tid < nb) ? bsum[tid] : 0;
    int x = v;
#pragma unroll
    for (int off = 1; off < 64; off <<= 1) {
        int t = __shfl_up(x, off, 64);
        if (lane >= off) x += t;
    }
    if (lane == 63) wsum[wid] = x;
    __syncthreads();
    if (tid < 16) {
        int y = wsum[tid];
#pragma unroll
        for (int off = 1; off < 16; off <<= 1) {
            int t = __shfl_up(y, off, 16);
            if (tid >= off) y += t;
        }
        wsum[tid] = y;
    }
    __syncthreads();
    int base = wid ? wsum[wid - 1] : 0;
    if (tid < nb) boff[tid] = base + x - v;
    if (tid == 0) rp[N] = wsum[15];
}

__global__ void scan_final(const int* __restrict__ deg, const int* __restrict__ boff,
                           int* __restrict__ rp, int* __restrict__ cursor, int N) {
    int tid = threadIdx.x, lane = tid & 63, wid = tid >> 6;
    int i = blockIdx.x * 256 + tid;
    int v = (i < N) ? deg[i] : 0;
    int x = v;
#pragma unroll
    for (int off = 1; off < 64; off <<= 1) {
        int t = __shfl_up(x, off, 64);
        if (lane >= off) x += t;
    }
    __shared__ int wsum[4];
    if (lane == 63) wsum[wid] = x;
    __syncthreads();
    int base = boff[blockIdx.x];
    for (int ww = 0; ww < wid; ww++) base += wsum[ww];
    int ex = base + x - v;
    if (i < N) { rp[i] = ex; cursor[i] = ex; }
}

__global__ void csr_fill(const int* __restrict__ src, const int* __restrict__ dst,
                         int* __restrict__ cursor, int* __restrict__ csr_src, int E) {
    int e = blockIdx.x * blockDim.x + threadIdx.x;
    if (e < E) {
        int pos = atomicAdd(&cursor[dst[e]], 1);
        csr_src[pos] = src[e];
    }
}

// B[K x N] f32 -> transposed bf16 hi/lo [N][Kpad] (zero-padded past K)
__global__ void prep_b(const float* __restrict__ B, unsigned short* __restrict__ Bth,
                       unsigned short* __restrict__ Btl, int K, int N, int Kpad) {
    int idx = blockIdx.x * 256 + threadIdx.x;
    if (idx >= N * Kpad) return;
    int n = idx / Kpad, k = idx - n * Kpad;
    float v = (k < K) ? B[(size_t)k * N + n] : 0.f;
    unsigned short h = f2bf(v);
    Bth[idx] = h;
    Btl[idx] = f2bf(v - bf2f(h));
}

// C tile [64 x 64] = A[M x K] @ B-half, split-bf16 MFMA, single-buffer LDS (20KB),
// 256 thr / 4 waves (2x2), wave tile 32x32. blockIdx.y selects the 64-col half.
// __launch_bounds__(256,8): force VGPR<=64 so 8 blocks/CU = 32 waves/CU.
template<int KT>
__global__ __launch_bounds__(256, 8) void gemm_s1(
    const float* __restrict__ A, const unsigned short* __restrict__ Bth,
    const unsigned short* __restrict__ Btl, float* __restrict__ C,
    int M, int K, int Kpad, int Nc) {
    constexpr int BM = 64, BN = 64, BK = 32, STR = 40;
    constexpr int MF = 2, NF = 2;

    __shared__ unsigned short AsH[BM][STR], AsL[BM][STR];
    __shared__ unsigned short BsH[BN][STR], BsL[BN][STR];

    const int tid = threadIdx.x;
    const int lane = tid & 63;
    const int w = tid >> 6;
    const int wrow = (w >> 1) * 32;
    const int wcol = (w & 1) * 32;
    const int bm = blockIdx.x * BM;
    const int bn0 = blockIdx.y * BN;
    const int lrow = lane & 15;
    const int lkq = (lane >> 4) * 8;
    const int aRow = tid >> 2;               // 64 rows, 4 thr/row
    const int aKc = (tid & 3) * 8;           // 8 f32 per thread
    const int bCol = tid >> 2;               // 64 cols, 4 thr/col
    const int bKc = (tid & 3) * 8;           // 8 u16 per kind per thread

    const bool aOk = (bm + aRow) < M;
    const float* aPtr = A + (size_t)(bm + aRow) * K;
    const unsigned short* bhPtr = Bth + (size_t)(bn0 + bCol) * Kpad + bKc;
    const unsigned short* blPtr = Btl + (size_t)(bn0 + bCol) * Kpad + bKc;

    f32x4 acc[MF][NF] = {};
    float4 af0, af1;
    u16x8 bfh, bfl;

    auto ISSUE = [&](int kt) {
        const int k0 = kt * BK;
        const float4 z = make_float4(0.f, 0.f, 0.f, 0.f);
        int kg = k0 + aKc;
        af0 = (aOk && kg + 4 <= K) ? *(const float4*)(aPtr + kg) : z;
        af1 = (aOk && kg + 8 <= K) ? *(const float4*)(aPtr + kg + 4) : z;
        bfh = *(const u16x8*)(bhPtr + k0);
        bfl = *(const u16x8*)(blPtr + k0);
    };
    auto WRITE = [&]() {
        ushort4 h4, l4;
        h4.x = f2bf(af0.x); l4.x = f2bf(af0.x - bf2f(h4.x));
        h4.y = f2bf(af0.y); l4.y = f2bf(af0.y - bf2f(h4.y));
        h4.z = f2bf(af0.z); l4.z = f2bf(af0.z - bf2f(h4.z));
        h4.w = f2bf(af0.w); l4.w = f2bf(af0.w - bf2f(h4.w));
        *(ushort4*)&AsH[aRow][aKc] = h4;
        *(ushort4*)&AsL[aRow][aKc] = l4;
        h4.x = f2bf(af1.x); l4.x = f2bf(af1.x - bf2f(h4.x));
        h4.y = f2bf(af1.y); l4.y = f2bf(af1.y - bf2f(h4.y));
        h4.z = f2bf(af1.z); l4.z = f2bf(af1.z - bf2f(h4.z));
        h4.w = f2bf(af1.w); l4.w = f2bf(af1.w - bf2f(h4.w));
        *(ushort4*)&AsH[aRow][aKc + 4] = h4;
        *(ushort4*)&AsL[aRow][aKc + 4] = l4;
        *(u16x8*)&BsH[bCol][bKc] = bfh;
        *(u16x8*)&BsL[bCol][bKc] = bfl;
    };
    auto COMPUTE = [&]() {
        short8 ah[MF], al[MF];
#pragma unroll
        for (int m = 0; m < MF; m++) {
            ah[m] = *(const short8*)&AsH[wrow + m * 16 + lrow][lkq];
            al[m] = *(const short8*)&AsL[wrow + m * 16 + lrow][lkq];
        }
#pragma unroll
        for (int n = 0; n < NF; n++) {
            short8 bh2 = *(const short8*)&BsH[wcol + n * 16 + lrow][lkq];
            short8 bl2 = *(const short8*)&BsL[wcol + n * 16 + lrow][lkq];
#pragma unroll
            for (int m = 0; m < MF; m++) {
                acc[m][n] = __builtin_amdgcn_mfma_f32_16x16x32_bf16(ah[m], bh2, acc[m][n], 0, 0, 0);
                acc[m][n] = __builtin_amdgcn_mfma_f32_16x16x32_bf16(al[m], bh2, acc[m][n], 0, 0, 0);
                acc[m][n] = __builtin_amdgcn_mfma_f32_16x16x32_bf16(ah[m], bl2, acc[m][n], 0, 0, 0);
            }
        }
    };

    ISSUE(0);
    WRITE();
    __syncthreads();
    for (int kt = 0; kt < KT; kt++) {
        COMPUTE();
        if (kt + 1 < KT) {
            __syncthreads();        // all reads of buffer done
            ISSUE(kt + 1);
            WRITE();                // drains loads (TLP covers the stall)
            __syncthreads();        // staged for everyone
        }
    }

    // store: C/D layout col=lane&15, row=(lane>>4)*4+q
#pragma unroll
    for (int m = 0; m < MF; m++)
#pragma unroll
        for (int n = 0; n < NF; n++)
#pragma unroll
            for (int q = 0; q < 4; q++) {
                int row = bm + wrow + m * 16 + (lane >> 4) * 4 + q;
                int col = bn0 + wcol + n * 16 + lrow;
                if (row < M) C[(size_t)row * Nc + col] = acc[m][n][q];
            }
}

// one wave per dst node, lanes across 128 features (float2/lane); fused self-loop+bias+relu
__global__ __launch_bounds__(256) void gather128(
    const int* __restrict__ rp, const int* __restrict__ csr,
    const float* __restrict__ dis, const float* __restrict__ h,
    const float* __restrict__ bias, float* __restrict__ out, int Nn) {
    int n = (blockIdx.x * 256 + threadIdx.x) >> 6;
    int lane = threadIdx.x & 63;
    if (n >= Nn) return;
    int beg = rp[n], end = rp[n + 1];
    float a0x = 0.f, a0y = 0.f, a1x = 0.f, a1y = 0.f;
    float a2x = 0.f, a2y = 0.f, a3x = 0.f, a3y = 0.f;
    int j = beg;
    for (; j + 3 < end; j += 4) {
        int s0 = csr[j], s1 = csr[j + 1], s2 = csr[j + 2], s3 = csr[j + 3];
        float w0 = dis[s0], w1 = dis[s1], w2 = dis[s2], w3 = dis[s3];
        float2 v0 = *(const float2*)&h[(size_t)s0 * 128 + lane * 2];
        float2 v1 = *(const float2*)&h[(size_t)s1 * 128 + lane * 2];
        float2 v2 = *(const float2*)&h[(size_t)s2 * 128 + lane * 2];
        float2 v3 = *(const float2*)&h[(size_t)s3 * 128 + lane * 2];
        a0x = fmaf(w0, v0.x, a0x); a0y = fmaf(w0, v0.y, a0y);
        a1x = fmaf(w1, v1.x, a1x); a1y = fmaf(w1, v1.y, a1y);
        a2x = fmaf(w2, v2.x, a2x); a2y = fmaf(w2, v2.y, a2y);
        a3x = fmaf(w3, v3.x, a3x); a3y = fmaf(w3, v3.y, a3y);
    }
    for (; j < end; j++) {
        int s = csr[j];
        float ww = dis[s];
        float2 v = *(const float2*)&h[(size_t)s * 128 + lane * 2];
        a0x = fmaf(ww, v.x, a0x); a0y = fmaf(ww, v.y, a0y);
    }
    float accx = (a0x + a1x) + (a2x + a3x);
    float accy = (a0y + a1y) + (a2y + a3y);
    float dn = dis[n];
    float2 hv = *(const float2*)&h[(size_t)n * 128 + lane * 2];
    float2 o;
    o.x = fmaxf(dn * (accx + dn * hv.x) + bias[lane * 2], 0.f);
    o.y = fmaxf(dn * (accy + dn * hv.y) + bias[lane * 2 + 1], 0.f);
    *(float2*)&out[(size_t)n * 128 + lane * 2] = o;
}

// one wave per dst node, lanes across 64 features; fused self-loop+bias (no relu)
__global__ __launch_bounds__(256) void gather64(
    const int* __restrict__ rp, const int* __restrict__ csr,
    const float* __restrict__ dis, const float* __restrict__ h,
    const float* __restrict__ bias, float* __restrict__ out, int Nn) {
    int n = (blockIdx.x * 256 + threadIdx.x) >> 6;
    int lane = threadIdx.x & 63;
    if (n >= Nn) return;
    int beg = rp[n], end = rp[n + 1];
    float a0 = 0.f, a1 = 0.f, a2 = 0.f, a3 = 0.f;
    int j = beg;
    for (; j + 3 < end; j += 4) {
        int s0 = csr[j], s1 = csr[j + 1], s2 = csr[j + 2], s3 = csr[j + 3];
        float w0 = dis[s0], w1 = dis[s1], w2 = dis[s2], w3 = dis[s3];
        float v0 = h[(size_t)s0 * 64 + lane];
        float v1 = h[(size_t)s1 * 64 + lane];
        float v2 = h[(size_t)s2 * 64 + lane];
        float v3 = h[(size_t)s3 * 64 + lane];
        a0 = fmaf(w0, v0, a0); a1 = fmaf(w1, v1, a1);
        a2 = fmaf(w2, v2, a2); a3 = fmaf(w3, v3, a3);
    }
    for (; j < end; j++) {
        int s = csr[j];
        a0 = fmaf(dis[s], h[(size_t)s * 64 + lane], a0);
    }
    float acc = (a0 + a1) + (a2 + a3);
    float dn = dis[n];
    float hv = h[(size_t)n * 64 + lane];
    out[(size_t)n * 64 + lane] = dn * (acc + dn * hv) + bias[lane];
}

extern "C" void kernel_launch(void* const* d_in, const int* in_sizes, int n_in,
                              void* d_out, int out_size, void* d_ws, size_t ws_size,
                              hipStream_t stream) {
    const float* x  = (const float*)d_in[0];
    const int*   ei = (const int*)d_in[1];
    const float* W1 = (const float*)d_in[2];
    const float* b1 = (const float*)d_in[3];
    const float* W2 = (const float*)d_in[4];
    const float* b2 = (const float*)d_in[5];

    const int IN = 500, H = 128, OUT = 64;
    const int Nn = in_sizes[0] / IN;     // 50000
    const int E  = in_sizes[1] / 2;      // 800000
    const int* src  = ei;
    const int* dstp = ei + E;

    const int Npad = ((Nn + 63) / 64) * 64;
    const int nb   = (Nn + 255) / 256;
    const int K1p  = 512, K2p = 128;

    // workspace layout (int units)
    int*   degdis  = (int*)d_ws;                 // N: int deg -> float dis in place
    int*   rp      = degdis + Npad;              // N+1
    int*   bsum    = rp + Npad + 64;             // 1024
    int*   boff    = bsum + 1024;                // 1024
    int*   cursor  = boff + 1024;                // N
    int*   csr_src = cursor + Npad;              // E
    unsigned short* Bt1h = (unsigned short*)(csr_src + ((E + 63) / 64) * 64);  // 128*512
    unsigned short* Bt1l = Bt1h + H * K1p;
    unsigned short* Bt2h = Bt1l + H * K1p;       // 64*128
    unsigned short* Bt2l = Bt2h + OUT * K2p;
    float* h1      = (float*)(Bt2l + OUT * K2p);
    float* agg1    = h1 + (size_t)Nn * H;
    float* h2      = h1;                         // reuse after layer-1 gather
    float* dis     = (float*)degdis;
    float* out     = (float*)d_out;

    // ---- degree / CSR build ----
    fill_int<<<(Nn + 255) / 256, 256, 0, stream>>>(degdis, 0, Nn);
    deg_accum_i<<<(E + 255) / 256, 256, 0, stream>>>(dstp, degdis, E);
    scan_part<<<nb, 256, 0, stream>>>(degdis, bsum, Nn);
    scan_top<<<1, 1024, 0, stream>>>(bsum, nb, boff, rp, Nn);
    scan_final<<<nb, 256, 0, stream>>>(degdis, boff, rp, cursor, Nn);
    make_dis<<<(Nn + 255) / 256, 256, 0, stream>>>(degdis, Nn);
    csr_fill<<<(E + 255) / 256, 256, 0, stream>>>(src, dstp, cursor, csr_src, E);

    // ---- weight prep (bf16 hi/lo, transposed) ----
    prep_b<<<(H * K1p + 255) / 256, 256, 0, stream>>>(W1, Bt1h, Bt1l, IN, H, K1p);
    prep_b<<<(OUT * K2p + 255) / 256, 256, 0, stream>>>(W2, Bt2h, Bt2l, H, OUT, K2p);

    // ---- layer 1: 64x64 tiles, 2 column-halves, KT=16 ----
    {
        dim3 g((Nn + 63) / 64, 2);
        gemm_s1<16><<<g, 256, 0, stream>>>(x, Bt1h, Bt1l, h1, Nn, IN, K1p, H);
    }
    gather128<<<(Nn + 3) / 4, 256, 0, stream>>>(rp, csr_src, dis, h1, b1, agg1, Nn);

    // ---- layer 2: 64x64 tiles, KT=4 ----
    {
        dim3 g((Nn + 63) / 64, 1);
        gemm_s1<4><<<g, 256, 0, stream>>>(agg1, Bt2h, Bt2l, h2, Nn, H, K2p, OUT);
    }
    gather64<<<(Nn + 3) / 4, 256, 0, stream>>>(rp, csr_src, dis, h2, b2, out, Nn);
}

// Round 10
// 291.237 us; speedup vs baseline: 1.0895x; 1.0895x over previous
//
#include <hip/hip_runtime.h>
#include <hip/hip_bf16.h>

// GCN 2-layer encoder. CSR-gather aggregation + split-bf16 MFMA GEMMs.
// GEMM: B staged in LDS once per 128-k group (L2: once total), A-fragments loaded
// directly global->register (double-buffered across groups). Barrier-light.

typedef __attribute__((ext_vector_type(4))) float f32x4;
typedef __attribute__((ext_vector_type(8))) short short8;
typedef __attribute__((ext_vector_type(8))) unsigned short u16x8;

static __device__ __forceinline__ unsigned short f2bf(float f) {
    unsigned int u = __float_as_uint(f);
    u += 0x7FFF + ((u >> 16) & 1);          // round-to-nearest-even
    return (unsigned short)(u >> 16);
}
static __device__ __forceinline__ float bf2f(unsigned short h) {
    return __uint_as_float(((unsigned int)h) << 16);
}

__global__ void fill_int(int* __restrict__ p, int v, int n) {
    int i = blockIdx.x * blockDim.x + threadIdx.x;
    if (i < n) p[i] = v;
}

__global__ void deg_accum_i(const int* __restrict__ dst, int* __restrict__ deg, int E) {
    int i = blockIdx.x * blockDim.x + threadIdx.x;
    if (i < E) atomicAdd(&deg[dst[i]], 1);
}

__global__ void make_dis(int* __restrict__ deg, int N) {
    int i = blockIdx.x * blockDim.x + threadIdx.x;
    if (i < N) {
        int d = deg[i];
        ((float*)deg)[i] = rsqrtf((float)(d + 1));
    }
}

// ---- hierarchical exclusive scan: deg[N] -> rp[N+1], cursor[N] ----
__global__ void scan_part(const int* __restrict__ deg, int* __restrict__ bsum, int N) {
    int tid = threadIdx.x, lane = tid & 63, wid = tid >> 6;
    int i = blockIdx.x * 256 + tid;
    int v = (i < N) ? deg[i] : 0;
#pragma unroll
    for (int off = 1; off < 64; off <<= 1) v += __shfl_xor(v, off, 64);
    __shared__ int ws[4];
    if (lane == 0) ws[wid] = v;
    __syncthreads();
    if (tid == 0) bsum[blockIdx.x] = ws[0] + ws[1] + ws[2] + ws[3];
}

__global__ __launch_bounds__(1024) void scan_top(const int* __restrict__ bsum, int nb,
                                                 int* __restrict__ boff, int* __restrict__ rp, int N) {
    __shared__ int wsum[16];
    int tid = threadIdx.x, lane = tid & 63, wid = tid >> 6;
    int v = (tid < nb) ? bsum[tid] : 0;
    int x = v;
#pragma unroll
    for (int off = 1; off < 64; off <<= 1) {
        int t = __shfl_up(x, off, 64);
        if (lane >= off) x += t;
    }
    if (lane == 63) wsum[wid] = x;
    __syncthreads();
    if (tid < 16) {
        int y = wsum[tid];
#pragma unroll
        for (int off = 1; off < 16; off <<= 1) {
            int t = __shfl_up(y, off, 16);
            if (tid >= off) y += t;
        }
        wsum[tid] = y;
    }
    __syncthreads();
    int base = wid ? wsum[wid - 1] : 0;
    if (tid < nb) boff[tid] = base + x - v;
    if (tid == 0) rp[N] = wsum[15];
}

__global__ void scan_final(const int* __restrict__ deg, const int* __restrict__ boff,
                           int* __restrict__ rp, int* __restrict__ cursor, int N) {
    int tid = threadIdx.x, lane = tid & 63, wid = tid >> 6;
    int i = blockIdx.x * 256 + tid;
    int v = (i < N) ? deg[i] : 0;
    int x = v;
#pragma unroll
    for (int off = 1; off < 64; off <<= 1) {
        int t = __shfl_up(x, off, 64);
        if (lane >= off) x += t;
    }
    __shared__ int wsum[4];
    if (lane == 63) wsum[wid] = x;
    __syncthreads();
    int base = boff[blockIdx.x];
    for (int ww = 0; ww < wid; ww++) base += wsum[ww];
    int ex = base + x - v;
    if (i < N) { rp[i] = ex; cursor[i] = ex; }
}

__global__ void csr_fill(const int* __restrict__ src, const int* __restrict__ dst,
                         int* __restrict__ cursor, int* __restrict__ csr_src, int E) {
    int e = blockIdx.x * blockDim.x + threadIdx.x;
    if (e < E) {
        int pos = atomicAdd(&cursor[dst[e]], 1);
        csr_src[pos] = src[e];
    }
}

// B[K x N] f32 -> transposed bf16 hi/lo [N][Kpad] (zero-padded past K)
__global__ void prep_b(const float* __restrict__ B, unsigned short* __restrict__ Bth,
                       unsigned short* __restrict__ Btl, int K, int N, int Kpad) {
    int idx = blockIdx.x * 256 + threadIdx.x;
    if (idx >= N * Kpad) return;
    int n = idx / Kpad, k = idx - n * Kpad;
    float v = (k < K) ? B[(size_t)k * N + n] : 0.f;
    unsigned short h = f2bf(v);
    Bth[idx] = h;
    Btl[idx] = f2bf(v - bf2f(h));
}

// C[M x BN] = A[M x K] @ B[K x BN], split-bf16 MFMA.
// BM=64 (4 waves x 16 rows), full-width BN. B staged in LDS per GK-k group (NG groups);
// A-fragments global->reg, double-buffered across groups. No barriers inside a group.
template<int BN, int GK, int NG, int MINW>
__global__ __launch_bounds__(256, MINW) void gemm_bs(
    const float* __restrict__ A, const unsigned short* __restrict__ Bth,
    const unsigned short* __restrict__ Btl, float* __restrict__ C,
    int M, int K, int Kpad) {
    constexpr int NF = BN / 16;          // col fragments per wave
    constexpr int GKP = GK + 8;          // LDS k-stride (ushorts): 272B rows, 2-way banks
    constexpr int TT = GK / 32;          // k-tiles per group
    constexpr int TPC = 256 / BN;        // staging threads per B column
    constexpr int SPT = GK / TPC;        // ushorts per thread per kind
    constexpr int NVB = SPT / 8;         // u16x8 per thread per kind
    static_assert(NVB >= 1, "staging shape");

    __shared__ unsigned short BsH[BN][GKP], BsL[BN][GKP];

    const int tid = threadIdx.x, lane = tid & 63, w = tid >> 6;
    const int lrow = lane & 15, lkq = (lane >> 4) * 8;
    const int bm = blockIdx.x * 64;
    const int myrow = bm + w * 16 + lrow;
    const bool aok = myrow < M;
    const float* aPtr = A + (size_t)myrow * K;

    const int sCol = tid / TPC;
    const int sKo = (tid % TPC) * SPT;
    const unsigned short* sbh = Bth + (size_t)sCol * Kpad + sKo;
    const unsigned short* sbl = Btl + (size_t)sCol * Kpad + sKo;

    f32x4 acc[NF] = {};
    float4 apf[2][TT][2];
    u16x8 rbh[NVB], rbl[NVB];

    auto PREFA = [&](int set, int g) {
        const float4 z = make_float4(0.f, 0.f, 0.f, 0.f);
#pragma unroll
        for (int t = 0; t < TT; t++) {
            int kg = g * GK + t * 32 + lkq;
            apf[set][t][0] = (aok && kg + 4 <= K) ? *(const float4*)(aPtr + kg) : z;
            apf[set][t][1] = (aok && kg + 8 <= K) ? *(const float4*)(aPtr + kg + 4) : z;
        }
    };
    auto LOADB = [&](int g) {
#pragma unroll
        for (int v = 0; v < NVB; v++) {
            rbh[v] = *(const u16x8*)(sbh + g * GK + v * 8);
            rbl[v] = *(const u16x8*)(sbl + g * GK + v * 8);
        }
    };
    auto WRITEB = [&]() {
#pragma unroll
        for (int v = 0; v < NVB; v++) {
            *(u16x8*)&BsH[sCol][sKo + v * 8] = rbh[v];
            *(u16x8*)&BsL[sCol][sKo + v * 8] = rbl[v];
        }
    };
    auto TILE = [&](int set, int t) {
        float fv[8] = {apf[set][t][0].x, apf[set][t][0].y, apf[set][t][0].z, apf[set][t][0].w,
                       apf[set][t][1].x, apf[set][t][1].y, apf[set][t][1].z, apf[set][t][1].w};
        short8 ah, al;
#pragma unroll
        for (int j = 0; j < 8; j++) {
            unsigned short hu = f2bf(fv[j]);
            ah[j] = (short)hu;
            al[j] = (short)f2bf(fv[j] - bf2f(hu));
        }
        short8 bh[NF], bl[NF];
#pragma unroll
        for (int n = 0; n < NF; n++) {
            bh[n] = *(const short8*)&BsH[n * 16 + lrow][t * 32 + lkq];
            bl[n] = *(const short8*)&BsL[n * 16 + lrow][t * 32 + lkq];
        }
#pragma unroll
        for (int n = 0; n < NF; n++)
            acc[n] = __builtin_amdgcn_mfma_f32_16x16x32_bf16(ah, bh[n], acc[n], 0, 0, 0);
#pragma unroll
        for (int n = 0; n < NF; n++)
            acc[n] = __builtin_amdgcn_mfma_f32_16x16x32_bf16(al, bh[n], acc[n], 0, 0, 0);
#pragma unroll
        for (int n = 0; n < NF; n++)
            acc[n] = __builtin_amdgcn_mfma_f32_16x16x32_bf16(ah, bl[n], acc[n], 0, 0, 0);
    };

    PREFA(0, 0);
    LOADB(0);
    WRITEB();
    __syncthreads();
#pragma unroll
    for (int g = 0; g < NG; g++) {
        if (g + 1 < NG) PREFA((g + 1) & 1, g + 1);   // next group's A flies under compute
#pragma unroll
        for (int t = 0; t < TT; t++) TILE(g & 1, t);
        if (g + 1 < NG) {
            LOADB(g + 1);
            __syncthreads();      // all waves done reading Bs[g]
            WRITEB();
            __syncthreads();      // Bs[g+1] visible
        }
    }

    // store: C/D layout col=lane&15, row=(lane>>4)*4+q
#pragma unroll
    for (int n = 0; n < NF; n++)
#pragma unroll
        for (int q = 0; q < 4; q++) {
            int row = bm + w * 16 + (lane >> 4) * 4 + q;
            int col = n * 16 + lrow;
            if (row < M) C[(size_t)row * BN + col] = acc[n][q];
        }
}

// one wave per dst node, lanes across 128 features (float2/lane); fused self-loop+bias+relu
__global__ __launch_bounds__(256) void gather128(
    const int* __restrict__ rp, const int* __restrict__ csr,
    const float* __restrict__ dis, const float* __restrict__ h,
    const float* __restrict__ bias, float* __restrict__ out, int Nn) {
    int n = (blockIdx.x * 256 + threadIdx.x) >> 6;
    int lane = threadIdx.x & 63;
    if (n >= Nn) return;
    int beg = rp[n], end = rp[n + 1];
    float a0x = 0.f, a0y = 0.f, a1x = 0.f, a1y = 0.f;
    float a2x = 0.f, a2y = 0.f, a3x = 0.f, a3y = 0.f;
    int j = beg;
    for (; j + 3 < end; j += 4) {
        int s0 = csr[j], s1 = csr[j + 1], s2 = csr[j + 2], s3 = csr[j + 3];
        float w0 = dis[s0], w1 = dis[s1], w2 = dis[s2], w3 = dis[s3];
        float2 v0 = *(const float2*)&h[(size_t)s0 * 128 + lane * 2];
        float2 v1 = *(const float2*)&h[(size_t)s1 * 128 + lane * 2];
        float2 v2 = *(const float2*)&h[(size_t)s2 * 128 + lane * 2];
        float2 v3 = *(const float2*)&h[(size_t)s3 * 128 + lane * 2];
        a0x = fmaf(w0, v0.x, a0x); a0y = fmaf(w0, v0.y, a0y);
        a1x = fmaf(w1, v1.x, a1x); a1y = fmaf(w1, v1.y, a1y);
        a2x = fmaf(w2, v2.x, a2x); a2y = fmaf(w2, v2.y, a2y);
        a3x = fmaf(w3, v3.x, a3x); a3y = fmaf(w3, v3.y, a3y);
    }
    for (; j < end; j++) {
        int s = csr[j];
        float ww = dis[s];
        float2 v = *(const float2*)&h[(size_t)s * 128 + lane * 2];
        a0x = fmaf(ww, v.x, a0x); a0y = fmaf(ww, v.y, a0y);
    }
    float accx = (a0x + a1x) + (a2x + a3x);
    float accy = (a0y + a1y) + (a2y + a3y);
    float dn = dis[n];
    float2 hv = *(const float2*)&h[(size_t)n * 128 + lane * 2];
    float2 o;
    o.x = fmaxf(dn * (accx + dn * hv.x) + bias[lane * 2], 0.f);
    o.y = fmaxf(dn * (accy + dn * hv.y) + bias[lane * 2 + 1], 0.f);
    *(float2*)&out[(size_t)n * 128 + lane * 2] = o;
}

// one wave per dst node, lanes across 64 features; fused self-loop+bias (no relu)
__global__ __launch_bounds__(256) void gather64(
    const int* __restrict__ rp, const int* __restrict__ csr,
    const float* __restrict__ dis, const float* __restrict__ h,
    const float* __restrict__ bias, float* __restrict__ out, int Nn) {
    int n = (blockIdx.x * 256 + threadIdx.x) >> 6;
    int lane = threadIdx.x & 63;
    if (n >= Nn) return;
    int beg = rp[n], end = rp[n + 1];
    float a0 = 0.f, a1 = 0.f, a2 = 0.f, a3 = 0.f;
    int j = beg;
    for (; j + 3 < end; j += 4) {
        int s0 = csr[j], s1 = csr[j + 1], s2 = csr[j + 2], s3 = csr[j + 3];
        float w0 = dis[s0], w1 = dis[s1], w2 = dis[s2], w3 = dis[s3];
        float v0 = h[(size_t)s0 * 64 + lane];
        float v1 = h[(size_t)s1 * 64 + lane];
        float v2 = h[(size_t)s2 * 64 + lane];
        float v3 = h[(size_t)s3 * 64 + lane];
        a0 = fmaf(w0, v0, a0); a1 = fmaf(w1, v1, a1);
        a2 = fmaf(w2, v2, a2); a3 = fmaf(w3, v3, a3);
    }
    for (; j < end; j++) {
        int s = csr[j];
        a0 = fmaf(dis[s], h[(size_t)s * 64 + lane], a0);
    }
    float acc = (a0 + a1) + (a2 + a3);
    float dn = dis[n];
    float hv = h[(size_t)n * 64 + lane];
    out[(size_t)n * 64 + lane] = dn * (acc + dn * hv) + bias[lane];
}

extern "C" void kernel_launch(void* const* d_in, const int* in_sizes, int n_in,
                              void* d_out, int out_size, void* d_ws, size_t ws_size,
                              hipStream_t stream) {
    const float* x  = (const float*)d_in[0];
    const int*   ei = (const int*)d_in[1];
    const float* W1 = (const float*)d_in[2];
    const float* b1 = (const float*)d_in[3];
    const float* W2 = (const float*)d_in[4];
    const float* b2 = (const float*)d_in[5];

    const int IN = 500, H = 128, OUT = 64;
    const int Nn = in_sizes[0] / IN;     // 50000
    const int E  = in_sizes[1] / 2;      // 800000
    const int* src  = ei;
    const int* dstp = ei + E;

    const int Npad = ((Nn + 63) / 64) * 64;
    const int nb   = (Nn + 255) / 256;
    const int K1p  = 512, K2p = 128;

    // workspace layout (int units)
    int*   degdis  = (int*)d_ws;                 // N: int deg -> float dis in place
    int*   rp      = degdis + Npad;              // N+1
    int*   bsum    = rp + Npad + 64;             // 1024
    int*   boff    = bsum + 1024;                // 1024
    int*   cursor  = boff + 1024;                // N
    int*   csr_src = cursor + Npad;              // E
    unsigned short* Bt1h = (unsigned short*)(csr_src + ((E + 63) / 64) * 64);  // 128*512
    unsigned short* Bt1l = Bt1h + H * K1p;
    unsigned short* Bt2h = Bt1l + H * K1p;       // 64*128
    unsigned short* Bt2l = Bt2h + OUT * K2p;
    float* h1      = (float*)(Bt2l + OUT * K2p);
    float* agg1    = h1 + (size_t)Nn * H;
    float* h2      = h1;                         // reuse after layer-1 gather
    float* dis     = (float*)degdis;
    float* out     = (float*)d_out;

    // ---- degree / CSR build ----
    fill_int<<<(Nn + 255) / 256, 256, 0, stream>>>(degdis, 0, Nn);
    deg_accum_i<<<(E + 255) / 256, 256, 0, stream>>>(dstp, degdis, E);
    scan_part<<<nb, 256, 0, stream>>>(degdis, bsum, Nn);
    scan_top<<<1, 1024, 0, stream>>>(bsum, nb, boff, rp, Nn);
    scan_final<<<nb, 256, 0, stream>>>(degdis, boff, rp, cursor, Nn);
    make_dis<<<(Nn + 255) / 256, 256, 0, stream>>>(degdis, Nn);
    csr_fill<<<(E + 255) / 256, 256, 0, stream>>>(src, dstp, cursor, csr_src, E);

    // ---- weight prep (bf16 hi/lo, transposed) ----
    prep_b<<<(H * K1p + 255) / 256, 256, 0, stream>>>(W1, Bt1h, Bt1l, IN, H, K1p);
    prep_b<<<(OUT * K2p + 255) / 256, 256, 0, stream>>>(W2, Bt2h, Bt2l, H, OUT, K2p);

    // ---- layer 1: BN=128, 4 groups of 128k; LDS 69.6KB -> 2 blocks/CU ----
    gemm_bs<128, 128, 4, 2><<<(Nn + 63) / 64, 256, 0, stream>>>(x, Bt1h, Bt1l, h1, Nn, IN, K1p);
    gather128<<<(Nn + 3) / 4, 256, 0, stream>>>(rp, csr_src, dis, h1, b1, agg1, Nn);

    // ---- layer 2: BN=64, single group (zero in-loop barriers); LDS 34.8KB -> 4 blocks/CU ----
    gemm_bs<64, 128, 1, 4><<<(Nn + 63) / 64, 256, 0, stream>>>(agg1, Bt2h, Bt2l, h2, Nn, H, K2p);
    gather64<<<(Nn + 3) / 4, 256, 0, stream>>>(rp, csr_src, dis, h2, b2, out, Nn);
}